// Round 12
// baseline (198.352 us; speedup 1.0000x reference)
//
#include <hip/hip_runtime.h>
#include <hip/hip_bf16.h>

typedef __attribute__((ext_vector_type(8))) short short8;
typedef __attribute__((ext_vector_type(4))) float floatx4;

__device__ __forceinline__ float bf2f(unsigned short b) {
    union { unsigned int u; float f; } v; v.u = ((unsigned int)b) << 16; return v.f;
}
__device__ __forceinline__ unsigned short f2bf(float f) {
    union { float f; unsigned int u; } v; v.f = f;
    unsigned int r = v.u + 0x7fffu + ((v.u >> 16) & 1u);   // RNE
    return (unsigned short)(r >> 16);
}
__device__ __forceinline__ unsigned int pk2bf(float a, float b) {
    __hip_bfloat162 h = __float22bfloat162_rn(make_float2(a, b));
    union { __hip_bfloat162 h; unsigned int u; } v; v.h = h; return v.u;
}

union Pack16 { uint4 v[2]; unsigned short u[16]; };
__device__ __forceinline__ void cvt16(const float* __restrict__ src, float s, Pack16& t) {
    float tmp[16];
    *(float4*)&tmp[0]  = ((const float4*)src)[0];
    *(float4*)&tmp[4]  = ((const float4*)src)[1];
    *(float4*)&tmp[8]  = ((const float4*)src)[2];
    *(float4*)&tmp[12] = ((const float4*)src)[3];
#pragma unroll
    for (int i = 0; i < 16; i++) t.u[i] = f2bf(tmp[i] * s);
}

#define MFMA16(a, b, c) __builtin_amdgcn_mfma_f32_16x16x32_bf16((a), (b), (c), 0, 0, 0)

// async global->LDS, 16 B/lane; dest = wave-uniform base + lane*16 (HW rule)
__device__ __forceinline__ void async16(const unsigned short* g, unsigned short* l) {
    __builtin_amdgcn_global_load_lds(
        (__attribute__((address_space(1))) void*)g,
        (__attribute__((address_space(3))) void*)l, 16, 0, 0);
}

// ---------------------------------------------------------------------------
// x f32 -> bf16 (one-time). (unchanged)
// ---------------------------------------------------------------------------
__global__ __launch_bounds__(256) void xcvt(
    const float* __restrict__ x, unsigned short* __restrict__ xb)
{
    const size_t i = ((size_t)blockIdx.x * 256 + threadIdx.x) * 8;
    float4 a = *(const float4*)(x + i), b = *(const float4*)(x + i + 4);
    union { uint4 v; unsigned short u[8]; } o;
    o.u[0] = f2bf(a.x); o.u[1] = f2bf(a.y); o.u[2] = f2bf(a.z); o.u[3] = f2bf(a.w);
    o.u[4] = f2bf(b.x); o.u[5] = f2bf(b.y); o.u[6] = f2bf(b.z); o.u[7] = f2bf(b.w);
    *(uint4*)(xb + i) = o.v;
}

// ---------------------------------------------------------------------------
// 64x64-tile GEMM, BK=64, async global_load_lds staging, XOR granule swizzle
// (same algebra as the validated 128-tile version: element (row,k) at
// shorts[row*64 + (kg ^ (row&7) ^ ((row>>4)&3))*8 + (k&7)]).
// 4 waves in 2x2 quadrants, each wave 2x2 MFMA 16x16 tiles.
// Smaller tile trades per-wave MFMA density for 2-6x more blocks/CU —
// the GEMMs are latency-bound at 1-3 blocks/CU (r11), not staging-bound.
// Grid: QKV (48,32) = 1536 blocks (6/CU); final (16,32) = 512 (2/CU).
// ---------------------------------------------------------------------------
template<bool BT_PRE, bool C_F32>
__global__ __launch_bounds__(256) void gemm64GL(
    const unsigned short* __restrict__ Abf,
    const void* __restrict__ B0, const void* __restrict__ B1, const void* __restrict__ B2,
    void* __restrict__ C0, void* __restrict__ C1, void* __restrict__ C2,
    int M, int N, int K)
{
    __shared__ __align__(16) unsigned short As[64 * 64];
    __shared__ __align__(16) unsigned short Bs[64 * 64];
    const int tid = threadIdx.x;
    const int sel = blockIdx.x >> 4;
    const int n0  = (blockIdx.x & 15) * 64;
    const int m0  = blockIdx.y * 64;
    const void* Bp = (sel == 0) ? B0 : (sel == 1) ? B1 : B2;
    void*       Cp = (sel == 0) ? C0 : (sel == 1) ? C1 : C2;

    const int wv = tid >> 6, lane = tid & 63;
    const int quad = lane >> 4, l15 = lane & 15;
    const int wm0 = (wv >> 1) * 32, wn0 = (wv & 1) * 32;

    floatx4 acc[2][2] = {};

    for (int k0 = 0; k0 < K; k0 += 64) {
        __syncthreads();
        // ---- stage A: 2 async 1KB copies per wave ----
        {
            const int rr = lane >> 3, pp = lane & 7;
#pragma unroll
            for (int j = 0; j < 2; j++) {
                const int r  = (wv * 2 + j) * 8 + rr;          // r&7 == rr
                const int kg = pp ^ rr ^ ((r >> 4) & 3);
                async16(Abf + (size_t)(m0 + r) * K + k0 + kg * 8,
                        &As[(wv * 2 + j) * 512]);
            }
        }
        // ---- stage B ----
        if (BT_PRE) {
            const int rr = lane >> 3, pp = lane & 7;
#pragma unroll
            for (int j = 0; j < 2; j++) {
                const int r  = (wv * 2 + j) * 8 + rr;
                const int kg = pp ^ rr ^ ((r >> 4) & 3);
                async16((const unsigned short*)Bp + (size_t)(n0 + r) * K + k0 + kg * 8,
                        &Bs[(wv * 2 + j) * 512]);
            }
        } else {
            const int kr = tid >> 2, nb = (tid & 3) * 16;
            float t[16];
            const float* b = (const float*)Bp + (size_t)(k0 + kr) * N + n0 + nb;
#pragma unroll
            for (int i = 0; i < 4; i++) *(float4*)&t[i * 4] = ((const float4*)b)[i];
            const int k3 = kr >> 3, k7 = kr & 7;
#pragma unroll
            for (int j = 0; j < 16; j++) {
                const int n  = nb + j;
                const int pg = k3 ^ (n & 7) ^ ((n >> 4) & 3);
                Bs[n * 64 + pg * 8 + k7] = f2bf(t[j]);
            }
        }
        __syncthreads();

#pragma unroll
        for (int ks = 0; ks < 2; ks++) {
            short8 af[2], bfr[2];
#pragma unroll
            for (int i = 0; i < 2; i++) {
                const int r = wm0 + i * 16 + l15;
                const int p = (ks * 4 + quad) ^ (r & 7) ^ ((r >> 4) & 3);
                af[i] = *(const short8*)&As[r * 64 + p * 8];
            }
#pragma unroll
            for (int i = 0; i < 2; i++) {
                const int r = wn0 + i * 16 + l15;
                const int p = (ks * 4 + quad) ^ (r & 7) ^ ((r >> 4) & 3);
                bfr[i] = *(const short8*)&Bs[r * 64 + p * 8];
            }
#pragma unroll
            for (int mt = 0; mt < 2; mt++)
#pragma unroll
                for (int nt = 0; nt < 2; nt++)
                    acc[mt][nt] = MFMA16(af[mt], bfr[nt], acc[mt][nt]);
        }
    }

#pragma unroll
    for (int mt = 0; mt < 2; mt++)
#pragma unroll
        for (int nt = 0; nt < 2; nt++)
#pragma unroll
            for (int r = 0; r < 4; r++) {
                const int row = m0 + wm0 + mt * 16 + quad * 4 + r;
                const int col = n0 + wn0 + nt * 16 + l15;
                if (C_F32)
                    ((float*)Cp)[(size_t)row * N + col] = acc[mt][nt][r];
                else
                    ((unsigned short*)Cp)[(size_t)row * N + col] = f2bf(acc[mt][nt][r]);
            }
}

// ---------------------------------------------------------------------------
// Weight transpose (unchanged)
// ---------------------------------------------------------------------------
__global__ __launch_bounds__(256) void wtrans(
    const float* __restrict__ W, unsigned short* __restrict__ WT, int Kd, int Nd)
{
    __shared__ __align__(16) unsigned short T[64][72];
    const int tid = threadIdx.x;
    const int n0 = blockIdx.x * 64, k0 = blockIdx.y * 64;
    {
        const int kr = tid >> 2, nc = (tid & 3) * 16;
        Pack16 t;
        cvt16(W + (size_t)(k0 + kr) * Nd + n0 + nc, 1.0f, t);
#pragma unroll
        for (int j = 0; j < 16; j++) T[nc + j][kr] = t.u[j];
    }
    __syncthreads();
    {
        const int nr = tid >> 2, kc = (tid & 3) * 16;
        uint4 x0 = *(const uint4*)&T[nr][kc];
        uint4 x1 = *(const uint4*)&T[nr][kc + 8];
        uint4* dst = (uint4*)(WT + (size_t)(n0 + nr) * Kd + k0 + kc);
        dst[0] = x0; dst[1] = x1;
    }
}

// ---------------------------------------------------------------------------
// Depthwise conv, layout-preserving. (unchanged)
// ---------------------------------------------------------------------------
__global__ __launch_bounds__(256) void conv_qk(
    const unsigned short* __restrict__ in, const float* __restrict__ cw,
    unsigned short* __restrict__ out)
{
    const int idx = blockIdx.x * 256 + threadIdx.x;
    const int w = idx >> 7, c0 = (idx & 127) * 8;
    union { uint4 v; unsigned short u[8]; } a = {}, b, c = {};
    b.v = *(const uint4*)(in + (size_t)w * 1024 + c0);
    if (w > 0)    a.v = *(const uint4*)(in + (size_t)(w - 1) * 1024 + c0);
    if (w < 2047) c.v = *(const uint4*)(in + (size_t)(w + 1) * 1024 + c0);
    union { uint4 v; unsigned short u[8]; } o;
#pragma unroll
    for (int i = 0; i < 8; i++) {
        const float* k3 = cw + (size_t)(c0 + i) * 3;
        o.u[i] = f2bf(bf2f(a.u[i]) * k3[0] + bf2f(b.u[i]) * k3[1] + bf2f(c.u[i]) * k3[2]);
    }
    *(uint4*)(out + (size_t)w * 1024 + c0) = o.v;
}

// ---------------------------------------------------------------------------
// Depthwise conv + per-head transpose -> vT [h*64+d][w]. (unchanged)
// ---------------------------------------------------------------------------
__global__ __launch_bounds__(256) void conv_vt(
    const unsigned short* __restrict__ in, const float* __restrict__ cw,
    unsigned short* __restrict__ vT)
{
    __shared__ __align__(16) unsigned short T[64][72];
    const int tid = threadIdx.x;
    const int w0 = blockIdx.x * 64, h = blockIdx.y;
    {
        const int wr = tid >> 2, c4 = (tid & 3) * 16;
        const int cg = h * 64 + c4;
        const int w = w0 + wr;
        union { uint4 v[2]; unsigned short u[16]; } a = {}, b, c = {};
        b.v[0] = *(const uint4*)(in + (size_t)w * 1024 + cg);
        b.v[1] = *(const uint4*)(in + (size_t)w * 1024 + cg + 8);
        if (w > 0) {
            a.v[0] = *(const uint4*)(in + (size_t)(w - 1) * 1024 + cg);
            a.v[1] = *(const uint4*)(in + (size_t)(w - 1) * 1024 + cg + 8);
        }
        if (w < 2047) {
            c.v[0] = *(const uint4*)(in + (size_t)(w + 1) * 1024 + cg);
            c.v[1] = *(const uint4*)(in + (size_t)(w + 1) * 1024 + cg + 8);
        }
#pragma unroll
        for (int i = 0; i < 16; i++) {
            const float* k3 = cw + (size_t)(cg + i) * 3;
            T[c4 + i][wr] = f2bf(bf2f(a.u[i]) * k3[0] + bf2f(b.u[i]) * k3[1] +
                                 bf2f(c.u[i]) * k3[2]);
        }
    }
    __syncthreads();
    {
        const int dr = tid >> 2, w4 = (tid & 3) * 16;
        uint4 x0 = *(const uint4*)&T[dr][w4];
        uint4 x1 = *(const uint4*)&T[dr][w4 + 8];
        uint4* dst = (uint4*)(vT + (size_t)(h * 64 + dr) * 2048 + w0 + w4);
        dst[0] = x0; dst[1] = x1;
    }
}

// ---------------------------------------------------------------------------
// Fused attention, wave-per-key-tile, Q-tile = 64. ROUND-6 BODY —
// proven 56 µs local optimum; r7/r8/r9 variants all regressed. Untouched.
// ---------------------------------------------------------------------------
__global__ __launch_bounds__(256, 2) void attn16(
    const unsigned short* __restrict__ qc, const unsigned short* __restrict__ kc,
    const unsigned short* __restrict__ vT, const float* __restrict__ er,
    unsigned short* __restrict__ outp)
{
    __shared__ __align__(16) unsigned char smem[70720];
    unsigned short* Qp = (unsigned short*)smem;

    const int tid = threadIdx.x;
    const int q0 = blockIdx.x * 64, h = blockIdx.y;
    const int wv = tid >> 6, lane = tid & 63;
    const int quad = lane >> 4, l15 = lane & 15;
    const float sc2 = 0.03125f * 1.44269504f;   // 1/sqrt(1024) * log2(e)

    {
        const int m = tid >> 2, c4 = (tid & 3) * 16;
        union { uint4 v[2]; unsigned short u[16]; } t;
        t.v[0] = *(const uint4*)(qc + (size_t)(q0 + m) * 1024 + h * 64 + c4);
        t.v[1] = *(const uint4*)(qc + (size_t)(q0 + m) * 1024 + h * 64 + c4 + 8);
#pragma unroll
        for (int i = 0; i < 16; i++) t.u[i] = f2bf(bf2f(t.u[i]) * sc2);
        *(uint4*)&Qp[m * 136 + c4]     = t.v[0];
        *(uint4*)&Qp[m * 136 + c4 + 8] = t.v[1];
        Pack16 e;
        cvt16(er + (size_t)m * 2048 + q0 + c4, sc2, e);
#pragma unroll
        for (int j = 0; j < 16; j++) Qp[(c4 + j) * 136 + 64 + m] = e.u[j];
    }
    __syncthreads();

    short8 Bq[4][4];
#pragma unroll
    for (int qm = 0; qm < 4; qm++)
#pragma unroll
        for (int ks = 0; ks < 4; ks++)
            Bq[qm][ks] = *(const short8*)&Qp[(qm * 16 + l15) * 136 + ks * 32 + quad * 8];

    unsigned short* Ps = (unsigned short*)(smem + 17408 + wv * 9216);

    floatx4 oacc[4][4] = {};
    float lp[4] = {0.f, 0.f, 0.f, 0.f};

    for (int i = 0; i < 8; i++) {
        const int kt = 4 * i + wv;
        floatx4 s[4][4] = {};
#pragma unroll
        for (int half = 0; half < 2; half++) {
            short8 Af[2][4];
#pragma unroll
            for (int kmh = 0; kmh < 2; kmh++)
#pragma unroll
                for (int ks = 0; ks < 4; ks++) {
                    const int row = kt * 64 + (half * 2 + kmh) * 16 + l15;
                    const unsigned short* src = (ks < 2) ? kc : qc;
                    const int col = h * 64 + (ks & 1) * 32 + quad * 8;
                    Af[kmh][ks] = *(const short8*)(src + (size_t)row * 1024 + col);
                }
#pragma unroll
            for (int ks = 0; ks < 4; ks++)
#pragma unroll
                for (int kmh = 0; kmh < 2; kmh++)
#pragma unroll
                    for (int qm = 0; qm < 4; qm++)
                        s[half * 2 + kmh][qm] =
                            MFMA16(Af[kmh][ks], Bq[qm][ks], s[half * 2 + kmh][qm]);
        }

#pragma unroll
        for (int km = 0; km < 4; km++)
#pragma unroll
            for (int qm = 0; qm < 4; qm++) {
                float p0 = exp2f(s[km][qm][0]);
                float p1 = exp2f(s[km][qm][1]);
                float p2 = exp2f(s[km][qm][2]);
                float p3 = exp2f(s[km][qm][3]);
                lp[qm] += (p0 + p1) + (p2 + p3);
                uint2 w;
                w.x = pk2bf(p0, p1);
                w.y = pk2bf(p2, p3);
                *(uint2*)&Ps[(qm * 16 + l15) * 72 + km * 16 + quad * 4] = w;
            }

#pragma unroll
        for (int ks = 0; ks < 2; ks++) {
            short8 Pa[4], Vb[4];
#pragma unroll
            for (int mt = 0; mt < 4; mt++)
                Pa[mt] = *(const short8*)&Ps[(mt * 16 + l15) * 72 + ks * 32 + quad * 8];
#pragma unroll
            for (int nt = 0; nt < 4; nt++)
                Vb[nt] = *(const short8*)(vT + (size_t)(h * 64 + nt * 16 + l15) * 2048 +
                                          kt * 64 + ks * 32 + quad * 8);
#pragma unroll
            for (int mt = 0; mt < 4; mt++)
#pragma unroll
                for (int nt = 0; nt < 4; nt++)
                    oacc[mt][nt] = MFMA16(Pa[mt], Vb[nt], oacc[mt][nt]);
        }
    }

#pragma unroll
    for (int qm = 0; qm < 4; qm++) {
        lp[qm] += __shfl_xor(lp[qm], 16);
        lp[qm] += __shfl_xor(lp[qm], 32);
    }
    __syncthreads();
    float* OfW = (float*)smem + wv * 4420;
#pragma unroll
    for (int mt = 0; mt < 4; mt++)
#pragma unroll
        for (int nt = 0; nt < 4; nt++) {
            floatx4 o = oacc[mt][nt];
            *(float4*)&OfW[(nt * 16 + l15) * 68 + mt * 16 + quad * 4] =
                make_float4(o[0], o[1], o[2], o[3]);
        }
    if (quad == 0) {
#pragma unroll
        for (int qm = 0; qm < 4; qm++) OfW[64 * 68 + qm * 16 + l15] = lp[qm];
    }
    __syncthreads();

    {
        const int d = wv * 16 + l15;
#pragma unroll
        for (int i4 = 0; i4 < 4; i4++) {
            float4 os = make_float4(0.f, 0.f, 0.f, 0.f);
            float4 ls = make_float4(0.f, 0.f, 0.f, 0.f);
#pragma unroll
            for (int s4 = 0; s4 < 4; s4++) {
                const float* R = (const float*)smem + s4 * 4420;
                float4 t  = *(const float4*)&R[d * 68 + quad * 16 + i4 * 4];
                float4 tl = *(const float4*)&R[64 * 68 + quad * 16 + i4 * 4];
                os.x += t.x;  os.y += t.y;  os.z += t.z;  os.w += t.w;
                ls.x += tl.x; ls.y += tl.y; ls.z += tl.z; ls.w += tl.w;
            }
            const int qb4 = quad * 16 + i4 * 4;
            const size_t colb = (size_t)h * 64 + d;
            outp[(size_t)(q0 + qb4 + 0) * 1024 + colb] = f2bf(os.x / ls.x);
            outp[(size_t)(q0 + qb4 + 1) * 1024 + colb] = f2bf(os.y / ls.y);
            outp[(size_t)(q0 + qb4 + 2) * 1024 + colb] = f2bf(os.z / ls.z);
            outp[(size_t)(q0 + qb4 + 3) * 1024 + colb] = f2bf(os.w / ls.w);
        }
    }
}

// ---------------------------------------------------------------------------
extern "C" void kernel_launch(void* const* d_in, const int* in_sizes, int n_in,
                              void* d_out, int out_size, void* d_ws, size_t ws_size,
                              hipStream_t stream)
{
    const float* x  = (const float*)d_in[0];
    const float* wq = (const float*)d_in[1];
    const float* wk = (const float*)d_in[2];
    const float* wv = (const float*)d_in[3];
    const float* wo = (const float*)d_in[4];
    const float* cw = (const float*)d_in[5];
    const float* er = (const float*)d_in[6];
    float* out = (float*)d_out;
    unsigned short* ws = (unsigned short*)d_ws;

    const size_t SZ = (size_t)2048 * 1024;
    unsigned short* A0 = ws;            // q_raw -> kc  -> woT
    unsigned short* A1 = ws + SZ;       // k_raw -> vT
    unsigned short* A2 = ws + 2 * SZ;   // v_raw -> attn_out
    unsigned short* A3 = ws + 3 * SZ;   // xbf   -> qc

    xcvt<<<1024, 256, 0, stream>>>(x, A3);                      // xbf
    gemm64GL<false, false><<<dim3(48, 32), 256, 0, stream>>>(
        A3, wq, wk, wv, A0, A1, A2, 2048, 1024, 1024);          // q/k/v raw
    conv_qk<<<1024, 256, 0, stream>>>(A0, cw, A3);              // qc (xbf dead)
    conv_qk<<<1024, 256, 0, stream>>>(A1, cw, A0);              // kc
    conv_vt<<<dim3(32, 16), 256, 0, stream>>>(A2, cw, A1);      // vT [h*64+d][w]
    attn16<<<dim3(32, 16), 256, 0, stream>>>(A3, A0, A1, er, A2);
    wtrans<<<dim3(16, 16), 256, 0, stream>>>(wo, A0, 1024, 1024);   // woT (kc dead)
    gemm64GL<true, true><<<dim3(16, 32), 256, 0, stream>>>(
        A2, A0, A0, A0, out, out, out, 2048, 1024, 1024);
}

// Round 13
// 179.412 us; speedup vs baseline: 1.1056x; 1.1056x over previous
//
#include <hip/hip_runtime.h>
#include <hip/hip_bf16.h>

typedef __attribute__((ext_vector_type(8))) short short8;
typedef __attribute__((ext_vector_type(4))) float floatx4;

__device__ __forceinline__ float bf2f(unsigned short b) {
    union { unsigned int u; float f; } v; v.u = ((unsigned int)b) << 16; return v.f;
}
__device__ __forceinline__ unsigned short f2bf(float f) {
    union { float f; unsigned int u; } v; v.f = f;
    unsigned int r = v.u + 0x7fffu + ((v.u >> 16) & 1u);   // RNE
    return (unsigned short)(r >> 16);
}
__device__ __forceinline__ unsigned int pk2bf(float a, float b) {
    __hip_bfloat162 h = __float22bfloat162_rn(make_float2(a, b));
    union { __hip_bfloat162 h; unsigned int u; } v; v.h = h; return v.u;
}

union Pack16 { uint4 v[2]; unsigned short u[16]; };
__device__ __forceinline__ void cvt16(const float* __restrict__ src, float s, Pack16& t) {
    float tmp[16];
    *(float4*)&tmp[0]  = ((const float4*)src)[0];
    *(float4*)&tmp[4]  = ((const float4*)src)[1];
    *(float4*)&tmp[8]  = ((const float4*)src)[2];
    *(float4*)&tmp[12] = ((const float4*)src)[3];
#pragma unroll
    for (int i = 0; i < 16; i++) t.u[i] = f2bf(tmp[i] * s);
}

#define MFMA16(a, b, c) __builtin_amdgcn_mfma_f32_16x16x32_bf16((a), (b), (c), 0, 0, 0)

// async global->LDS, 16 B/lane; dest = wave-uniform base + lane*16 (HW rule)
__device__ __forceinline__ void async16(const unsigned short* g, unsigned short* l) {
    __builtin_amdgcn_global_load_lds(
        (__attribute__((address_space(1))) void*)g,
        (__attribute__((address_space(3))) void*)l, 16, 0, 0);
}

// ---------------------------------------------------------------------------
// x f32 -> bf16 (one-time).
// ---------------------------------------------------------------------------
__global__ __launch_bounds__(256) void xcvt(
    const float* __restrict__ x, unsigned short* __restrict__ xb)
{
    const size_t i = ((size_t)blockIdx.x * 256 + threadIdx.x) * 8;
    float4 a = *(const float4*)(x + i), b = *(const float4*)(x + i + 4);
    union { uint4 v; unsigned short u[8]; } o;
    o.u[0] = f2bf(a.x); o.u[1] = f2bf(a.y); o.u[2] = f2bf(a.z); o.u[3] = f2bf(a.w);
    o.u[4] = f2bf(b.x); o.u[5] = f2bf(b.y); o.u[6] = f2bf(b.z); o.u[7] = f2bf(b.w);
    *(uint4*)(xb + i) = o.v;
}

// ---------------------------------------------------------------------------
// 128(M)x64(N)-tile GEMM, BK=64, fully-async global_load_lds staging (m97).
// LDS: unpadded, XOR granule swizzle: element (row,k) at
// shorts[row*64 + (kg ^ (row&7) ^ ((row>>4)&3))*8 + (k&7)].
// Both A (bf16 [M][K]) and B (bf16 pre-transposed [N][K]) staged async.
// 128x64 tile is the proven sweet spot (r12: 64x64 regressed -8us; r5:
// 128x128 grid-starved). Do not change tile shape without new evidence.
// ---------------------------------------------------------------------------
template<bool C_F32>
__global__ __launch_bounds__(256) void gemmGL(
    const unsigned short* __restrict__ Abf,
    const unsigned short* __restrict__ B0, const unsigned short* __restrict__ B1,
    const unsigned short* __restrict__ B2,
    void* __restrict__ C0, void* __restrict__ C1, void* __restrict__ C2,
    int M, int N, int K)
{
    __shared__ __align__(16) unsigned short As[128 * 64];
    __shared__ __align__(16) unsigned short Bs[64 * 64];
    const int tid = threadIdx.x;
    const int sel = blockIdx.x >> 4;
    const int n0  = (blockIdx.x & 15) * 64;
    const int m0  = blockIdx.y * 128;
    const unsigned short* Bp = (sel == 0) ? B0 : (sel == 1) ? B1 : B2;
    void*                 Cp = (sel == 0) ? C0 : (sel == 1) ? C1 : C2;

    const int wv = tid >> 6, lane = tid & 63;
    const int quad = lane >> 4, l15 = lane & 15;
    const int wm0 = (wv >> 1) * 64, wn0 = (wv & 1) * 32;

    floatx4 acc[4][2] = {};

    for (int k0 = 0; k0 < K; k0 += 64) {
        __syncthreads();
        // ---- stage A: 4 async 1KB copies per wave ----
        {
            const int rr = lane >> 3, pp = lane & 7;
#pragma unroll
            for (int j = 0; j < 4; j++) {
                const int r  = (wv * 4 + j) * 8 + rr;          // r&7 == rr
                const int kg = pp ^ rr ^ ((r >> 4) & 3);
                async16(Abf + (size_t)(m0 + r) * K + k0 + kg * 8,
                        &As[(wv * 4 + j) * 512]);
            }
        }
        // ---- stage B: 2 async 1KB copies per wave ----
        {
            const int rr = lane >> 3, pp = lane & 7;
#pragma unroll
            for (int j = 0; j < 2; j++) {
                const int r  = (wv * 2 + j) * 8 + rr;
                const int kg = pp ^ rr ^ ((r >> 4) & 3);
                async16(Bp + (size_t)(n0 + r) * K + k0 + kg * 8,
                        &Bs[(wv * 2 + j) * 512]);
            }
        }
        __syncthreads();

#pragma unroll
        for (int ks = 0; ks < 2; ks++) {
            short8 af[4], bfr[2];
#pragma unroll
            for (int i = 0; i < 4; i++) {
                const int r = wm0 + i * 16 + l15;
                const int p = (ks * 4 + quad) ^ (r & 7) ^ ((r >> 4) & 3);
                af[i] = *(const short8*)&As[r * 64 + p * 8];
            }
#pragma unroll
            for (int i = 0; i < 2; i++) {
                const int r = wn0 + i * 16 + l15;
                const int p = (ks * 4 + quad) ^ (r & 7) ^ ((r >> 4) & 3);
                bfr[i] = *(const short8*)&Bs[r * 64 + p * 8];
            }
#pragma unroll
            for (int mt = 0; mt < 4; mt++)
#pragma unroll
                for (int nt = 0; nt < 2; nt++)
                    acc[mt][nt] = MFMA16(af[mt], bfr[nt], acc[mt][nt]);
        }
    }

#pragma unroll
    for (int mt = 0; mt < 4; mt++)
#pragma unroll
        for (int nt = 0; nt < 2; nt++)
#pragma unroll
            for (int r = 0; r < 4; r++) {
                const int row = m0 + wm0 + mt * 16 + quad * 4 + r;
                const int col = n0 + wn0 + nt * 16 + l15;
                if (C_F32)
                    ((float*)Cp)[(size_t)row * N + col] = acc[mt][nt][r];
                else
                    ((unsigned short*)Cp)[(size_t)row * N + col] = f2bf(acc[mt][nt][r]);
            }
}

// ---------------------------------------------------------------------------
// Weight transpose: W f32 [K][N] -> WT bf16 [N][K], 64x64 LDS tiles.
// wtrans3 does wq/wk/wv in one launch (z selects), dst packed contiguously.
// ---------------------------------------------------------------------------
__device__ __forceinline__ void wtrans_body(
    const float* __restrict__ W, unsigned short* __restrict__ WT,
    int n0, int k0, int tid)
{
    __shared__ __align__(16) unsigned short T[64][72];
    {
        const int kr = tid >> 2, nc = (tid & 3) * 16;
        Pack16 t;
        cvt16(W + (size_t)(k0 + kr) * 1024 + n0 + nc, 1.0f, t);
#pragma unroll
        for (int j = 0; j < 16; j++) T[nc + j][kr] = t.u[j];
    }
    __syncthreads();
    {
        const int nr = tid >> 2, kc = (tid & 3) * 16;
        uint4 x0 = *(const uint4*)&T[nr][kc];
        uint4 x1 = *(const uint4*)&T[nr][kc + 8];
        uint4* dst = (uint4*)(WT + (size_t)(n0 + nr) * 1024 + k0 + kc);
        dst[0] = x0; dst[1] = x1;
    }
}

__global__ __launch_bounds__(256) void wtrans(
    const float* __restrict__ W, unsigned short* __restrict__ WT)
{
    wtrans_body(W, WT, blockIdx.x * 64, blockIdx.y * 64, threadIdx.x);
}

__global__ __launch_bounds__(256) void wtrans3(
    const float* __restrict__ W0, const float* __restrict__ W1,
    const float* __restrict__ W2, unsigned short* __restrict__ WT)
{
    const int z = blockIdx.z;
    const float* W = (z == 0) ? W0 : (z == 1) ? W1 : W2;
    wtrans_body(W, WT + (size_t)z * 1024 * 1024,
                blockIdx.x * 64, blockIdx.y * 64, threadIdx.x);
}

// ---------------------------------------------------------------------------
// All three depthwise convs (k=3, same-pad along w) in ONE launch so they
// overlap: bx<1024: q_raw->qc ([w][c]); bx<2048: k_raw->kc ([w][c]);
// bx>=2048: v_raw->vT ([h*64+d][w], LDS transpose). Outputs routed to
// non-aliasing buffers (qc->A3, kc/vT->d_out scratch) so no RAW hazards.
// ---------------------------------------------------------------------------
__global__ __launch_bounds__(256) void conv_all(
    const unsigned short* __restrict__ q_raw, const unsigned short* __restrict__ k_raw,
    const unsigned short* __restrict__ v_raw, const float* __restrict__ cw,
    unsigned short* __restrict__ qc, unsigned short* __restrict__ kc,
    unsigned short* __restrict__ vT)
{
    __shared__ __align__(16) unsigned short T[64][72];
    const int bx = blockIdx.x;
    if (bx < 2048) {
        const unsigned short* in  = (bx < 1024) ? q_raw : k_raw;
        unsigned short*       out = (bx < 1024) ? qc : kc;
        const int idx = (bx & 1023) * 256 + threadIdx.x;
        const int w = idx >> 7, c0 = (idx & 127) * 8;
        union { uint4 v; unsigned short u[8]; } a = {}, b, c = {};
        b.v = *(const uint4*)(in + (size_t)w * 1024 + c0);
        if (w > 0)    a.v = *(const uint4*)(in + (size_t)(w - 1) * 1024 + c0);
        if (w < 2047) c.v = *(const uint4*)(in + (size_t)(w + 1) * 1024 + c0);
        union { uint4 v; unsigned short u[8]; } o;
#pragma unroll
        for (int i = 0; i < 8; i++) {
            const float* k3 = cw + (size_t)(c0 + i) * 3;
            o.u[i] = f2bf(bf2f(a.u[i]) * k3[0] + bf2f(b.u[i]) * k3[1] +
                          bf2f(c.u[i]) * k3[2]);
        }
        *(uint4*)(out + (size_t)w * 1024 + c0) = o.v;
    } else {
        const int iv = bx - 2048;
        const int w0 = (iv & 31) * 64, h = iv >> 5;
        const int tid = threadIdx.x;
        {
            const int wr = tid >> 2, c4 = (tid & 3) * 16;
            const int cg = h * 64 + c4;
            const int w = w0 + wr;
            union { uint4 v[2]; unsigned short u[16]; } a = {}, b, c = {};
            b.v[0] = *(const uint4*)(v_raw + (size_t)w * 1024 + cg);
            b.v[1] = *(const uint4*)(v_raw + (size_t)w * 1024 + cg + 8);
            if (w > 0) {
                a.v[0] = *(const uint4*)(v_raw + (size_t)(w - 1) * 1024 + cg);
                a.v[1] = *(const uint4*)(v_raw + (size_t)(w - 1) * 1024 + cg + 8);
            }
            if (w < 2047) {
                c.v[0] = *(const uint4*)(v_raw + (size_t)(w + 1) * 1024 + cg);
                c.v[1] = *(const uint4*)(v_raw + (size_t)(w + 1) * 1024 + cg + 8);
            }
#pragma unroll
            for (int i = 0; i < 16; i++) {
                const float* k3 = cw + (size_t)(cg + i) * 3;
                T[c4 + i][wr] = f2bf(bf2f(a.u[i]) * k3[0] + bf2f(b.u[i]) * k3[1] +
                                     bf2f(c.u[i]) * k3[2]);
            }
        }
        __syncthreads();
        {
            const int dr = tid >> 2, w4 = (tid & 3) * 16;
            uint4 x0 = *(const uint4*)&T[dr][w4];
            uint4 x1 = *(const uint4*)&T[dr][w4 + 8];
            uint4* dst = (uint4*)(vT + (size_t)(h * 64 + dr) * 2048 + w0 + w4);
            dst[0] = x0; dst[1] = x1;
        }
    }
}

// ---------------------------------------------------------------------------
// Fused attention, wave-per-key-tile, Q-tile = 64. ROUND-6 BODY —
// proven 56 µs local optimum; r7/r8/r9 variants all regressed. Untouched.
// ---------------------------------------------------------------------------
__global__ __launch_bounds__(256, 2) void attn16(
    const unsigned short* __restrict__ qc, const unsigned short* __restrict__ kc,
    const unsigned short* __restrict__ vT, const float* __restrict__ er,
    unsigned short* __restrict__ outp)
{
    __shared__ __align__(16) unsigned char smem[70720];
    unsigned short* Qp = (unsigned short*)smem;

    const int tid = threadIdx.x;
    const int q0 = blockIdx.x * 64, h = blockIdx.y;
    const int wv = tid >> 6, lane = tid & 63;
    const int quad = lane >> 4, l15 = lane & 15;
    const float sc2 = 0.03125f * 1.44269504f;   // 1/sqrt(1024) * log2(e)

    {
        const int m = tid >> 2, c4 = (tid & 3) * 16;
        union { uint4 v[2]; unsigned short u[16]; } t;
        t.v[0] = *(const uint4*)(qc + (size_t)(q0 + m) * 1024 + h * 64 + c4);
        t.v[1] = *(const uint4*)(qc + (size_t)(q0 + m) * 1024 + h * 64 + c4 + 8);
#pragma unroll
        for (int i = 0; i < 16; i++) t.u[i] = f2bf(bf2f(t.u[i]) * sc2);
        *(uint4*)&Qp[m * 136 + c4]     = t.v[0];
        *(uint4*)&Qp[m * 136 + c4 + 8] = t.v[1];
        Pack16 e;
        cvt16(er + (size_t)m * 2048 + q0 + c4, sc2, e);
#pragma unroll
        for (int j = 0; j < 16; j++) Qp[(c4 + j) * 136 + 64 + m] = e.u[j];
    }
    __syncthreads();

    short8 Bq[4][4];
#pragma unroll
    for (int qm = 0; qm < 4; qm++)
#pragma unroll
        for (int ks = 0; ks < 4; ks++)
            Bq[qm][ks] = *(const short8*)&Qp[(qm * 16 + l15) * 136 + ks * 32 + quad * 8];

    unsigned short* Ps = (unsigned short*)(smem + 17408 + wv * 9216);

    floatx4 oacc[4][4] = {};
    float lp[4] = {0.f, 0.f, 0.f, 0.f};

    for (int i = 0; i < 8; i++) {
        const int kt = 4 * i + wv;
        floatx4 s[4][4] = {};
#pragma unroll
        for (int half = 0; half < 2; half++) {
            short8 Af[2][4];
#pragma unroll
            for (int kmh = 0; kmh < 2; kmh++)
#pragma unroll
                for (int ks = 0; ks < 4; ks++) {
                    const int row = kt * 64 + (half * 2 + kmh) * 16 + l15;
                    const unsigned short* src = (ks < 2) ? kc : qc;
                    const int col = h * 64 + (ks & 1) * 32 + quad * 8;
                    Af[kmh][ks] = *(const short8*)(src + (size_t)row * 1024 + col);
                }
#pragma unroll
            for (int ks = 0; ks < 4; ks++)
#pragma unroll
                for (int kmh = 0; kmh < 2; kmh++)
#pragma unroll
                    for (int qm = 0; qm < 4; qm++)
                        s[half * 2 + kmh][qm] =
                            MFMA16(Af[kmh][ks], Bq[qm][ks], s[half * 2 + kmh][qm]);
        }

#pragma unroll
        for (int km = 0; km < 4; km++)
#pragma unroll
            for (int qm = 0; qm < 4; qm++) {
                float p0 = exp2f(s[km][qm][0]);
                float p1 = exp2f(s[km][qm][1]);
                float p2 = exp2f(s[km][qm][2]);
                float p3 = exp2f(s[km][qm][3]);
                lp[qm] += (p0 + p1) + (p2 + p3);
                uint2 w;
                w.x = pk2bf(p0, p1);
                w.y = pk2bf(p2, p3);
                *(uint2*)&Ps[(qm * 16 + l15) * 72 + km * 16 + quad * 4] = w;
            }

#pragma unroll
        for (int ks = 0; ks < 2; ks++) {
            short8 Pa[4], Vb[4];
#pragma unroll
            for (int mt = 0; mt < 4; mt++)
                Pa[mt] = *(const short8*)&Ps[(mt * 16 + l15) * 72 + ks * 32 + quad * 8];
#pragma unroll
            for (int nt = 0; nt < 4; nt++)
                Vb[nt] = *(const short8*)(vT + (size_t)(h * 64 + nt * 16 + l15) * 2048 +
                                          kt * 64 + ks * 32 + quad * 8);
#pragma unroll
            for (int mt = 0; mt < 4; mt++)
#pragma unroll
                for (int nt = 0; nt < 4; nt++)
                    oacc[mt][nt] = MFMA16(Pa[mt], Vb[nt], oacc[mt][nt]);
        }
    }

#pragma unroll
    for (int qm = 0; qm < 4; qm++) {
        lp[qm] += __shfl_xor(lp[qm], 16);
        lp[qm] += __shfl_xor(lp[qm], 32);
    }
    __syncthreads();
    float* OfW = (float*)smem + wv * 4420;
#pragma unroll
    for (int mt = 0; mt < 4; mt++)
#pragma unroll
        for (int nt = 0; nt < 4; nt++) {
            floatx4 o = oacc[mt][nt];
            *(float4*)&OfW[(nt * 16 + l15) * 68 + mt * 16 + quad * 4] =
                make_float4(o[0], o[1], o[2], o[3]);
        }
    if (quad == 0) {
#pragma unroll
        for (int qm = 0; qm < 4; qm++) OfW[64 * 68 + qm * 16 + l15] = lp[qm];
    }
    __syncthreads();

    {
        const int d = wv * 16 + l15;
#pragma unroll
        for (int i4 = 0; i4 < 4; i4++) {
            float4 os = make_float4(0.f, 0.f, 0.f, 0.f);
            float4 ls = make_float4(0.f, 0.f, 0.f, 0.f);
#pragma unroll
            for (int s4 = 0; s4 < 4; s4++) {
                const float* R = (const float*)smem + s4 * 4420;
                float4 t  = *(const float4*)&R[d * 68 + quad * 16 + i4 * 4];
                float4 tl = *(const float4*)&R[64 * 68 + quad * 16 + i4 * 4];
                os.x += t.x;  os.y += t.y;  os.z += t.z;  os.w += t.w;
                ls.x += tl.x; ls.y += tl.y; ls.z += tl.z; ls.w += tl.w;
            }
            const int qb4 = quad * 16 + i4 * 4;
            const size_t colb = (size_t)h * 64 + d;
            outp[(size_t)(q0 + qb4 + 0) * 1024 + colb] = f2bf(os.x / ls.x);
            outp[(size_t)(q0 + qb4 + 1) * 1024 + colb] = f2bf(os.y / ls.y);
            outp[(size_t)(q0 + qb4 + 2) * 1024 + colb] = f2bf(os.z / ls.z);
            outp[(size_t)(q0 + qb4 + 3) * 1024 + colb] = f2bf(os.w / ls.w);
        }
    }
}

// ---------------------------------------------------------------------------
// Buffer plan (ws = 4 x 4 MB regions, PLUS d_out (8 MB) as scratch until the
// final GEMM writes it):
//   phase 1: xcvt x->A3; wtrans3 wq/wk/wv -> d_out[0:6MB] (bf16 [N][K] x3)
//   phase 2: QKV gemm (A=A3 async, B=d_out wT async) -> A0,A1,A2
//   phase 3: conv_all: A0->A3 (qc), A1->d_out.lo (kc), A2->d_out.hi (vT)
//            [weights in d_out are dead after phase 2]
//   phase 4: wtrans wo->A0 (woT); attn16(A3, d_out.lo, d_out.hi) -> A2
//   phase 5: final gemm (A=A2, B=A0) -> d_out (overwrites scratch, now dead)
// ---------------------------------------------------------------------------
extern "C" void kernel_launch(void* const* d_in, const int* in_sizes, int n_in,
                              void* d_out, int out_size, void* d_ws, size_t ws_size,
                              hipStream_t stream)
{
    const float* x  = (const float*)d_in[0];
    const float* wq = (const float*)d_in[1];
    const float* wk = (const float*)d_in[2];
    const float* wv = (const float*)d_in[3];
    const float* wo = (const float*)d_in[4];
    const float* cw = (const float*)d_in[5];
    const float* er = (const float*)d_in[6];
    float* out = (float*)d_out;
    unsigned short* ws = (unsigned short*)d_ws;
    unsigned short* ob = (unsigned short*)d_out;   // bf16 scratch view of d_out

    const size_t SZ = (size_t)2048 * 1024;         // 2M shorts = 4 MB
    const size_t WT = (size_t)1024 * 1024;         // one transposed weight
    unsigned short* A0 = ws;            // q_raw -> woT
    unsigned short* A1 = ws + SZ;       // k_raw
    unsigned short* A2 = ws + 2 * SZ;   // v_raw -> attn_out
    unsigned short* A3 = ws + 3 * SZ;   // xbf   -> qc

    xcvt<<<1024, 256, 0, stream>>>(x, A3);                          // xbf
    wtrans3<<<dim3(16, 16, 3), 256, 0, stream>>>(wq, wk, wv, ob);   // wT -> d_out
    gemmGL<false><<<dim3(48, 16), 256, 0, stream>>>(
        A3, ob, ob + WT, ob + 2 * WT, A0, A1, A2, 2048, 1024, 1024);
    conv_all<<<2560, 256, 0, stream>>>(A0, A1, A2, cw,
                                       A3, ob, ob + 2 * SZ / 2);    // qc, kc, vT
    wtrans<<<dim3(16, 16), 256, 0, stream>>>(wo, A0);               // woT
    attn16<<<dim3(32, 16), 256, 0, stream>>>(A3, ob, ob + SZ, er, A2);
    gemmGL<true><<<dim3(16, 16), 256, 0, stream>>>(
        A2, A0, A0, A0, out, out, out, 2048, 1024, 1024);
}

// Round 14
// 174.375 us; speedup vs baseline: 1.1375x; 1.0289x over previous
//
#include <hip/hip_runtime.h>
#include <hip/hip_bf16.h>

typedef __attribute__((ext_vector_type(8))) short short8;
typedef __attribute__((ext_vector_type(4))) float floatx4;

__device__ __forceinline__ float bf2f(unsigned short b) {
    union { unsigned int u; float f; } v; v.u = ((unsigned int)b) << 16; return v.f;
}
__device__ __forceinline__ unsigned short f2bf(float f) {
    union { float f; unsigned int u; } v; v.f = f;
    unsigned int r = v.u + 0x7fffu + ((v.u >> 16) & 1u);   // RNE
    return (unsigned short)(r >> 16);
}
__device__ __forceinline__ unsigned int pk2bf(float a, float b) {
    __hip_bfloat162 h = __float22bfloat162_rn(make_float2(a, b));
    union { __hip_bfloat162 h; unsigned int u; } v; v.h = h; return v.u;
}

union Pack16 { uint4 v[2]; unsigned short u[16]; };
__device__ __forceinline__ void cvt16(const float* __restrict__ src, float s, Pack16& t) {
    float tmp[16];
    *(float4*)&tmp[0]  = ((const float4*)src)[0];
    *(float4*)&tmp[4]  = ((const float4*)src)[1];
    *(float4*)&tmp[8]  = ((const float4*)src)[2];
    *(float4*)&tmp[12] = ((const float4*)src)[3];
#pragma unroll
    for (int i = 0; i < 16; i++) t.u[i] = f2bf(tmp[i] * s);
}

#define MFMA16(a, b, c) __builtin_amdgcn_mfma_f32_16x16x32_bf16((a), (b), (c), 0, 0, 0)

// async global->LDS, 16 B/lane; dest = wave-uniform base + lane*16 (HW rule)
__device__ __forceinline__ void async16(const unsigned short* g, unsigned short* l) {
    __builtin_amdgcn_global_load_lds(
        (__attribute__((address_space(1))) void*)g,
        (__attribute__((address_space(3))) void*)l, 16, 0, 0);
}

// ---------------------------------------------------------------------------
// Weight-transpose tile body: W f32 [K][N] -> WT bf16 [N][K], 64x64 tile.
// ---------------------------------------------------------------------------
__device__ __forceinline__ void wtrans_body(
    const float* __restrict__ W, unsigned short* __restrict__ WT,
    int n0, int k0, int tid)
{
    __shared__ __align__(16) unsigned short T[64][72];
    {
        const int kr = tid >> 2, nc = (tid & 3) * 16;
        Pack16 t;
        cvt16(W + (size_t)(k0 + kr) * 1024 + n0 + nc, 1.0f, t);
#pragma unroll
        for (int j = 0; j < 16; j++) T[nc + j][kr] = t.u[j];
    }
    __syncthreads();
    {
        const int nr = tid >> 2, kc = (tid & 3) * 16;
        uint4 x0 = *(const uint4*)&T[nr][kc];
        uint4 x1 = *(const uint4*)&T[nr][kc + 8];
        uint4* dst = (uint4*)(WT + (size_t)(n0 + nr) * 1024 + k0 + kc);
        dst[0] = x0; dst[1] = x1;
    }
}

// ---------------------------------------------------------------------------
// Prep: one launch does xcvt (x f32->bf16, blocks 0..1023) AND wq/wk/wv
// transpose (blocks 1024..1791; 256 tiles each). Independent outputs.
// ---------------------------------------------------------------------------
__global__ __launch_bounds__(256) void prep(
    const float* __restrict__ x, unsigned short* __restrict__ xb,
    const float* __restrict__ W0, const float* __restrict__ W1,
    const float* __restrict__ W2, unsigned short* __restrict__ WT)
{
    const int bx = blockIdx.x;
    if (bx < 1024) {
        const size_t i = ((size_t)bx * 256 + threadIdx.x) * 8;
        float4 a = *(const float4*)(x + i), b = *(const float4*)(x + i + 4);
        union { uint4 v; unsigned short u[8]; } o;
        o.u[0] = f2bf(a.x); o.u[1] = f2bf(a.y); o.u[2] = f2bf(a.z); o.u[3] = f2bf(a.w);
        o.u[4] = f2bf(b.x); o.u[5] = f2bf(b.y); o.u[6] = f2bf(b.z); o.u[7] = f2bf(b.w);
        *(uint4*)(xb + i) = o.v;
    } else {
        const int t = bx - 1024;           // 0..767
        const int z = t >> 8;              // weight select
        const int tt = t & 255;            // 16x16 tiles
        const float* W = (z == 0) ? W0 : (z == 1) ? W1 : W2;
        wtrans_body(W, WT + (size_t)z * 1024 * 1024,
                    (tt & 15) * 64, (tt >> 4) * 64, threadIdx.x);
    }
}

__global__ __launch_bounds__(256) void wtrans(
    const float* __restrict__ W, unsigned short* __restrict__ WT)
{
    wtrans_body(W, WT, blockIdx.x * 64, blockIdx.y * 64, threadIdx.x);
}

// ---------------------------------------------------------------------------
// 128(M)x64(N)-tile GEMM, BK=64, fully-async global_load_lds staging (m97).
// LDS: unpadded, XOR granule swizzle: element (row,k) at
// shorts[row*64 + (kg ^ (row&7) ^ ((row>>4)&3))*8 + (k&7)].
// PROVEN config for QKV (r13, 179.4 total). Do not change tile shape.
// ---------------------------------------------------------------------------
template<bool C_F32>
__global__ __launch_bounds__(256) void gemmGL(
    const unsigned short* __restrict__ Abf,
    const unsigned short* __restrict__ B0, const unsigned short* __restrict__ B1,
    const unsigned short* __restrict__ B2,
    void* __restrict__ C0, void* __restrict__ C1, void* __restrict__ C2,
    int M, int N, int K)
{
    __shared__ __align__(16) unsigned short As[128 * 64];
    __shared__ __align__(16) unsigned short Bs[64 * 64];
    const int tid = threadIdx.x;
    const int sel = blockIdx.x >> 4;
    const int n0  = (blockIdx.x & 15) * 64;
    const int m0  = blockIdx.y * 128;
    const unsigned short* Bp = (sel == 0) ? B0 : (sel == 1) ? B1 : B2;
    void*                 Cp = (sel == 0) ? C0 : (sel == 1) ? C1 : C2;

    const int wv = tid >> 6, lane = tid & 63;
    const int quad = lane >> 4, l15 = lane & 15;
    const int wm0 = (wv >> 1) * 64, wn0 = (wv & 1) * 32;

    floatx4 acc[4][2] = {};

    for (int k0 = 0; k0 < K; k0 += 64) {
        __syncthreads();
        {
            const int rr = lane >> 3, pp = lane & 7;
#pragma unroll
            for (int j = 0; j < 4; j++) {
                const int r  = (wv * 4 + j) * 8 + rr;
                const int kg = pp ^ rr ^ ((r >> 4) & 3);
                async16(Abf + (size_t)(m0 + r) * K + k0 + kg * 8,
                        &As[(wv * 4 + j) * 512]);
            }
#pragma unroll
            for (int j = 0; j < 2; j++) {
                const int r  = (wv * 2 + j) * 8 + rr;
                const int kg = pp ^ rr ^ ((r >> 4) & 3);
                async16(Bp + (size_t)(n0 + r) * K + k0 + kg * 8,
                        &Bs[(wv * 2 + j) * 512]);
            }
        }
        __syncthreads();

#pragma unroll
        for (int ks = 0; ks < 2; ks++) {
            short8 af[4], bfr[2];
#pragma unroll
            for (int i = 0; i < 4; i++) {
                const int r = wm0 + i * 16 + l15;
                const int p = (ks * 4 + quad) ^ (r & 7) ^ ((r >> 4) & 3);
                af[i] = *(const short8*)&As[r * 64 + p * 8];
            }
#pragma unroll
            for (int i = 0; i < 2; i++) {
                const int r = wn0 + i * 16 + l15;
                const int p = (ks * 4 + quad) ^ (r & 7) ^ ((r >> 4) & 3);
                bfr[i] = *(const short8*)&Bs[r * 64 + p * 8];
            }
#pragma unroll
            for (int mt = 0; mt < 4; mt++)
#pragma unroll
                for (int nt = 0; nt < 2; nt++)
                    acc[mt][nt] = MFMA16(af[mt], bfr[nt], acc[mt][nt]);
        }
    }

#pragma unroll
    for (int mt = 0; mt < 4; mt++)
#pragma unroll
        for (int nt = 0; nt < 2; nt++)
#pragma unroll
            for (int r = 0; r < 4; r++) {
                const int row = m0 + wm0 + mt * 16 + quad * 4 + r;
                const int col = n0 + wn0 + nt * 16 + l15;
                if (C_F32)
                    ((float*)Cp)[(size_t)row * N + col] = acc[mt][nt][r];
                else
                    ((unsigned short*)Cp)[(size_t)row * N + col] = f2bf(acc[mt][nt][r]);
            }
}

// ---------------------------------------------------------------------------
// 64x64-tile fully-async GEMM for the FINAL matmul only: its 128-tile grid
// is 256 blocks = 1 block/CU (worst-provisioned dispatch). 64-tile -> 512
// blocks = 2/CU. (r12 tested 64² on BOTH gemms and lost net — QKV stays 128.)
// ---------------------------------------------------------------------------
__global__ __launch_bounds__(256) void gemm64F(
    const unsigned short* __restrict__ Abf, const unsigned short* __restrict__ Bp,
    float* __restrict__ Cp, int M, int N, int K)
{
    __shared__ __align__(16) unsigned short As[64 * 64];
    __shared__ __align__(16) unsigned short Bs[64 * 64];
    const int tid = threadIdx.x;
    const int n0  = blockIdx.x * 64;
    const int m0  = blockIdx.y * 64;
    const int wv = tid >> 6, lane = tid & 63;
    const int quad = lane >> 4, l15 = lane & 15;
    const int wm0 = (wv >> 1) * 32, wn0 = (wv & 1) * 32;

    floatx4 acc[2][2] = {};

    for (int k0 = 0; k0 < K; k0 += 64) {
        __syncthreads();
        {
            const int rr = lane >> 3, pp = lane & 7;
#pragma unroll
            for (int j = 0; j < 2; j++) {
                const int r  = (wv * 2 + j) * 8 + rr;
                const int kg = pp ^ rr ^ ((r >> 4) & 3);
                async16(Abf + (size_t)(m0 + r) * K + k0 + kg * 8,
                        &As[(wv * 2 + j) * 512]);
                async16(Bp + (size_t)(n0 + r) * K + k0 + kg * 8,
                        &Bs[(wv * 2 + j) * 512]);
            }
        }
        __syncthreads();

#pragma unroll
        for (int ks = 0; ks < 2; ks++) {
            short8 af[2], bfr[2];
#pragma unroll
            for (int i = 0; i < 2; i++) {
                const int r = wm0 + i * 16 + l15;
                const int p = (ks * 4 + quad) ^ (r & 7) ^ ((r >> 4) & 3);
                af[i] = *(const short8*)&As[r * 64 + p * 8];
            }
#pragma unroll
            for (int i = 0; i < 2; i++) {
                const int r = wn0 + i * 16 + l15;
                const int p = (ks * 4 + quad) ^ (r & 7) ^ ((r >> 4) & 3);
                bfr[i] = *(const short8*)&Bs[r * 64 + p * 8];
            }
#pragma unroll
            for (int mt = 0; mt < 2; mt++)
#pragma unroll
                for (int nt = 0; nt < 2; nt++)
                    acc[mt][nt] = MFMA16(af[mt], bfr[nt], acc[mt][nt]);
        }
    }

#pragma unroll
    for (int mt = 0; mt < 2; mt++)
#pragma unroll
        for (int nt = 0; nt < 2; nt++)
#pragma unroll
            for (int r = 0; r < 4; r++) {
                const int row = m0 + wm0 + mt * 16 + quad * 4 + r;
                const int col = n0 + wn0 + nt * 16 + l15;
                Cp[(size_t)row * N + col] = acc[mt][nt][r];
            }
}

// ---------------------------------------------------------------------------
// All three depthwise convs in ONE launch. (unchanged from r13)
// ---------------------------------------------------------------------------
__global__ __launch_bounds__(256) void conv_all(
    const unsigned short* __restrict__ q_raw, const unsigned short* __restrict__ k_raw,
    const unsigned short* __restrict__ v_raw, const float* __restrict__ cw,
    unsigned short* __restrict__ qc, unsigned short* __restrict__ kc,
    unsigned short* __restrict__ vT)
{
    __shared__ __align__(16) unsigned short T[64][72];
    const int bx = blockIdx.x;
    if (bx < 2048) {
        const unsigned short* in  = (bx < 1024) ? q_raw : k_raw;
        unsigned short*       out = (bx < 1024) ? qc : kc;
        const int idx = (bx & 1023) * 256 + threadIdx.x;
        const int w = idx >> 7, c0 = (idx & 127) * 8;
        union { uint4 v; unsigned short u[8]; } a = {}, b, c = {};
        b.v = *(const uint4*)(in + (size_t)w * 1024 + c0);
        if (w > 0)    a.v = *(const uint4*)(in + (size_t)(w - 1) * 1024 + c0);
        if (w < 2047) c.v = *(const uint4*)(in + (size_t)(w + 1) * 1024 + c0);
        union { uint4 v; unsigned short u[8]; } o;
#pragma unroll
        for (int i = 0; i < 8; i++) {
            const float* k3 = cw + (size_t)(c0 + i) * 3;
            o.u[i] = f2bf(bf2f(a.u[i]) * k3[0] + bf2f(b.u[i]) * k3[1] +
                          bf2f(c.u[i]) * k3[2]);
        }
        *(uint4*)(out + (size_t)w * 1024 + c0) = o.v;
    } else {
        const int iv = bx - 2048;
        const int w0 = (iv & 31) * 64, h = iv >> 5;
        const int tid = threadIdx.x;
        {
            const int wr = tid >> 2, c4 = (tid & 3) * 16;
            const int cg = h * 64 + c4;
            const int w = w0 + wr;
            union { uint4 v[2]; unsigned short u[16]; } a = {}, b, c = {};
            b.v[0] = *(const uint4*)(v_raw + (size_t)w * 1024 + cg);
            b.v[1] = *(const uint4*)(v_raw + (size_t)w * 1024 + cg + 8);
            if (w > 0) {
                a.v[0] = *(const uint4*)(v_raw + (size_t)(w - 1) * 1024 + cg);
                a.v[1] = *(const uint4*)(v_raw + (size_t)(w - 1) * 1024 + cg + 8);
            }
            if (w < 2047) {
                c.v[0] = *(const uint4*)(v_raw + (size_t)(w + 1) * 1024 + cg);
                c.v[1] = *(const uint4*)(v_raw + (size_t)(w + 1) * 1024 + cg + 8);
            }
#pragma unroll
            for (int i = 0; i < 16; i++) {
                const float* k3 = cw + (size_t)(cg + i) * 3;
                T[c4 + i][wr] = f2bf(bf2f(a.u[i]) * k3[0] + bf2f(b.u[i]) * k3[1] +
                                     bf2f(c.u[i]) * k3[2]);
            }
        }
        __syncthreads();
        {
            const int dr = tid >> 2, w4 = (tid & 3) * 16;
            uint4 x0 = *(const uint4*)&T[dr][w4];
            uint4 x1 = *(const uint4*)&T[dr][w4 + 8];
            uint4* dst = (uint4*)(vT + (size_t)(h * 64 + dr) * 2048 + w0 + w4);
            dst[0] = x0; dst[1] = x1;
        }
    }
}

// ---------------------------------------------------------------------------
// Fused attention, wave-per-key-tile, Q-tile = 64. ROUND-6 BODY —
// proven 56 µs local optimum; r7/r8/r9 variants all regressed. Untouched.
// ---------------------------------------------------------------------------
__global__ __launch_bounds__(256, 2) void attn16(
    const unsigned short* __restrict__ qc, const unsigned short* __restrict__ kc,
    const unsigned short* __restrict__ vT, const float* __restrict__ er,
    unsigned short* __restrict__ outp)
{
    __shared__ __align__(16) unsigned char smem[70720];
    unsigned short* Qp = (unsigned short*)smem;

    const int tid = threadIdx.x;
    const int q0 = blockIdx.x * 64, h = blockIdx.y;
    const int wv = tid >> 6, lane = tid & 63;
    const int quad = lane >> 4, l15 = lane & 15;
    const float sc2 = 0.03125f * 1.44269504f;   // 1/sqrt(1024) * log2(e)

    {
        const int m = tid >> 2, c4 = (tid & 3) * 16;
        union { uint4 v[2]; unsigned short u[16]; } t;
        t.v[0] = *(const uint4*)(qc + (size_t)(q0 + m) * 1024 + h * 64 + c4);
        t.v[1] = *(const uint4*)(qc + (size_t)(q0 + m) * 1024 + h * 64 + c4 + 8);
#pragma unroll
        for (int i = 0; i < 16; i++) t.u[i] = f2bf(bf2f(t.u[i]) * sc2);
        *(uint4*)&Qp[m * 136 + c4]     = t.v[0];
        *(uint4*)&Qp[m * 136 + c4 + 8] = t.v[1];
        Pack16 e;
        cvt16(er + (size_t)m * 2048 + q0 + c4, sc2, e);
#pragma unroll
        for (int j = 0; j < 16; j++) Qp[(c4 + j) * 136 + 64 + m] = e.u[j];
    }
    __syncthreads();

    short8 Bq[4][4];
#pragma unroll
    for (int qm = 0; qm < 4; qm++)
#pragma unroll
        for (int ks = 0; ks < 4; ks++)
            Bq[qm][ks] = *(const short8*)&Qp[(qm * 16 + l15) * 136 + ks * 32 + quad * 8];

    unsigned short* Ps = (unsigned short*)(smem + 17408 + wv * 9216);

    floatx4 oacc[4][4] = {};
    float lp[4] = {0.f, 0.f, 0.f, 0.f};

    for (int i = 0; i < 8; i++) {
        const int kt = 4 * i + wv;
        floatx4 s[4][4] = {};
#pragma unroll
        for (int half = 0; half < 2; half++) {
            short8 Af[2][4];
#pragma unroll
            for (int kmh = 0; kmh < 2; kmh++)
#pragma unroll
                for (int ks = 0; ks < 4; ks++) {
                    const int row = kt * 64 + (half * 2 + kmh) * 16 + l15;
                    const unsigned short* src = (ks < 2) ? kc : qc;
                    const int col = h * 64 + (ks & 1) * 32 + quad * 8;
                    Af[kmh][ks] = *(const short8*)(src + (size_t)row * 1024 + col);
                }
#pragma unroll
            for (int ks = 0; ks < 4; ks++)
#pragma unroll
                for (int kmh = 0; kmh < 2; kmh++)
#pragma unroll
                    for (int qm = 0; qm < 4; qm++)
                        s[half * 2 + kmh][qm] =
                            MFMA16(Af[kmh][ks], Bq[qm][ks], s[half * 2 + kmh][qm]);
        }

#pragma unroll
        for (int km = 0; km < 4; km++)
#pragma unroll
            for (int qm = 0; qm < 4; qm++) {
                float p0 = exp2f(s[km][qm][0]);
                float p1 = exp2f(s[km][qm][1]);
                float p2 = exp2f(s[km][qm][2]);
                float p3 = exp2f(s[km][qm][3]);
                lp[qm] += (p0 + p1) + (p2 + p3);
                uint2 w;
                w.x = pk2bf(p0, p1);
                w.y = pk2bf(p2, p3);
                *(uint2*)&Ps[(qm * 16 + l15) * 72 + km * 16 + quad * 4] = w;
            }

#pragma unroll
        for (int ks = 0; ks < 2; ks++) {
            short8 Pa[4], Vb[4];
#pragma unroll
            for (int mt = 0; mt < 4; mt++)
                Pa[mt] = *(const short8*)&Ps[(mt * 16 + l15) * 72 + ks * 32 + quad * 8];
#pragma unroll
            for (int nt = 0; nt < 4; nt++)
                Vb[nt] = *(const short8*)(vT + (size_t)(h * 64 + nt * 16 + l15) * 2048 +
                                          kt * 64 + ks * 32 + quad * 8);
#pragma unroll
            for (int mt = 0; mt < 4; mt++)
#pragma unroll
                for (int nt = 0; nt < 4; nt++)
                    oacc[mt][nt] = MFMA16(Pa[mt], Vb[nt], oacc[mt][nt]);
        }
    }

#pragma unroll
    for (int qm = 0; qm < 4; qm++) {
        lp[qm] += __shfl_xor(lp[qm], 16);
        lp[qm] += __shfl_xor(lp[qm], 32);
    }
    __syncthreads();
    float* OfW = (float*)smem + wv * 4420;
#pragma unroll
    for (int mt = 0; mt < 4; mt++)
#pragma unroll
        for (int nt = 0; nt < 4; nt++) {
            floatx4 o = oacc[mt][nt];
            *(float4*)&OfW[(nt * 16 + l15) * 68 + mt * 16 + quad * 4] =
                make_float4(o[0], o[1], o[2], o[3]);
        }
    if (quad == 0) {
#pragma unroll
        for (int qm = 0; qm < 4; qm++) OfW[64 * 68 + qm * 16 + l15] = lp[qm];
    }
    __syncthreads();

    {
        const int d = wv * 16 + l15;
#pragma unroll
        for (int i4 = 0; i4 < 4; i4++) {
            float4 os = make_float4(0.f, 0.f, 0.f, 0.f);
            float4 ls = make_float4(0.f, 0.f, 0.f, 0.f);
#pragma unroll
            for (int s4 = 0; s4 < 4; s4++) {
                const float* R = (const float*)smem + s4 * 4420;
                float4 t  = *(const float4*)&R[d * 68 + quad * 16 + i4 * 4];
                float4 tl = *(const float4*)&R[64 * 68 + quad * 16 + i4 * 4];
                os.x += t.x;  os.y += t.y;  os.z += t.z;  os.w += t.w;
                ls.x += tl.x; ls.y += tl.y; ls.z += tl.z; ls.w += tl.w;
            }
            const int qb4 = quad * 16 + i4 * 4;
            const size_t colb = (size_t)h * 64 + d;
            outp[(size_t)(q0 + qb4 + 0) * 1024 + colb] = f2bf(os.x / ls.x);
            outp[(size_t)(q0 + qb4 + 1) * 1024 + colb] = f2bf(os.y / ls.y);
            outp[(size_t)(q0 + qb4 + 2) * 1024 + colb] = f2bf(os.z / ls.z);
            outp[(size_t)(q0 + qb4 + 3) * 1024 + colb] = f2bf(os.w / ls.w);
        }
    }
}

// ---------------------------------------------------------------------------
// Buffer plan (r13-proven, plus prep fusion):
//   phase 1: prep: xcvt x->A3; wq/wk/wv^T -> d_out[0:6MB]
//   phase 2: QKV gemm (A=A3, B=d_out wT, both async) -> A0,A1,A2
//   phase 3: conv_all: A0->A3 (qc), A1->d_out.lo (kc), A2->d_out.hi (vT)
//   phase 4: wtrans wo->A0; attn16(A3, d_out.lo, d_out.hi) -> A2
//   phase 5: final gemm64F (A=A2, B=A0) -> d_out
// ---------------------------------------------------------------------------
extern "C" void kernel_launch(void* const* d_in, const int* in_sizes, int n_in,
                              void* d_out, int out_size, void* d_ws, size_t ws_size,
                              hipStream_t stream)
{
    const float* x  = (const float*)d_in[0];
    const float* wq = (const float*)d_in[1];
    const float* wk = (const float*)d_in[2];
    const float* wv = (const float*)d_in[3];
    const float* wo = (const float*)d_in[4];
    const float* cw = (const float*)d_in[5];
    const float* er = (const float*)d_in[6];
    float* out = (float*)d_out;
    unsigned short* ws = (unsigned short*)d_ws;
    unsigned short* ob = (unsigned short*)d_out;   // bf16 scratch view of d_out

    const size_t SZ = (size_t)2048 * 1024;         // 2M shorts = 4 MB
    const size_t WT = (size_t)1024 * 1024;         // one transposed weight
    unsigned short* A0 = ws;            // q_raw -> woT
    unsigned short* A1 = ws + SZ;       // k_raw
    unsigned short* A2 = ws + 2 * SZ;   // v_raw -> attn_out
    unsigned short* A3 = ws + 3 * SZ;   // xbf   -> qc

    prep<<<1792, 256, 0, stream>>>(x, A3, wq, wk, wv, ob);
    gemmGL<false><<<dim3(48, 16), 256, 0, stream>>>(
        A3, ob, ob + WT, ob + 2 * WT, A0, A1, A2, 2048, 1024, 1024);
    conv_all<<<2560, 256, 0, stream>>>(A0, A1, A2, cw, A3, ob, ob + SZ);
    wtrans<<<dim3(16, 16), 256, 0, stream>>>(wo, A0);               // woT
    attn16<<<dim3(32, 16), 256, 0, stream>>>(A3, ob, ob + SZ, er, A2);
    gemm64F<<<dim3(16, 32), 256, 0, stream>>>(A2, A0, out, 2048, 1024, 1024);
}